// Round 4
// baseline (2972.637 us; speedup 1.0000x reference)
//
#include <hip/hip_runtime.h>

#define NN 32768
#define NE 1048576

typedef __bf16 bf16_t;
typedef __bf16 bf16x8 __attribute__((ext_vector_type(8)));
typedef __bf16 bf16x4 __attribute__((ext_vector_type(4)));
typedef float f32x4 __attribute__((ext_vector_type(4)));

// ---------------- absmax(edges_init) + receiver counts (fused) ----------------
__global__ __launch_bounds__(256) void stats_kernel(const float* __restrict__ x,
                                                    const int* __restrict__ recv,
                                                    float* __restrict__ norm,
                                                    int* __restrict__ counts) {
  int idx = blockIdx.x * 256 + threadIdx.x;
  float4 v = reinterpret_cast<const float4*>(x)[idx];
  float m = fmaxf(fmaxf(fabsf(v.x), fabsf(v.y)), fmaxf(fabsf(v.z), fabsf(v.w)));
#pragma unroll
  for (int off = 32; off > 0; off >>= 1) m = fmaxf(m, __shfl_xor(m, off, 64));
  if ((threadIdx.x & 63) == 0)
    atomicMax(reinterpret_cast<unsigned int*>(norm), __float_as_uint(m));
  int4 r = reinterpret_cast<const int4*>(recv)[idx];
  atomicAdd(&counts[r.x], 1);
  atomicAdd(&counts[r.y], 1);
  atomicAdd(&counts[r.z], 1);
  atomicAdd(&counts[r.w], 1);
}

// ---------------- all weights -> bf16 fragment layout, one buffer ----------------
// frag f: lane l holds W[k = kt*32 + (l>>4)*8 + i][col = nt*16 + (l&15)], i=0..7
// layout: [Weu1: f 0-23][Weu2: 24-31][Wee2: 32-39][Wd1: 40-47]
__global__ __launch_bounds__(256) void prep_all_kernel(const float* __restrict__ Weu1,
                                                       const float* __restrict__ Weu2,
                                                       const float* __restrict__ Wee2,
                                                       const float* __restrict__ Wd1,
                                                       bf16_t* __restrict__ dst) {
  int idx = blockIdx.x * 256 + threadIdx.x;  // 48*512 = 24576 total
  int i = idx & 7, lane = (idx >> 3) & 63, f = idx >> 9;
  const float* W;
  int fl;
  if (f < 24)      { W = Weu1; fl = f; }
  else if (f < 32) { W = Weu2; fl = f - 24; }
  else if (f < 40) { W = Wee2; fl = f - 32; }
  else             { W = Wd1;  fl = f - 40; }
  int kt = fl >> 2, nt = fl & 3;
  int k = kt * 32 + ((lane >> 4) << 3) + i;
  int col = nt * 16 + (lane & 15);
  dst[idx] = (bf16_t)W[k * 64 + col];
}

// ---------------- node encoder (fp32, exact) ----------------
__global__ __launch_bounds__(256) void node_encode_kernel(
    const float* __restrict__ nodes, const float* __restrict__ W1, const float* __restrict__ b1,
    const float* __restrict__ W2, const float* __restrict__ b2,
    float* __restrict__ n_f32, bf16_t* __restrict__ n_bf) {
  __shared__ float hs[4][64];
  int wid = threadIdx.x >> 6, k = threadIdx.x & 63;
  int node = blockIdx.x * 4 + wid;
  float x = nodes[node];
  hs[wid][k] = fmaxf(x * W1[k] + b1[k], 0.0f);
  __syncthreads();
  float acc = b2[k];
#pragma unroll 8
  for (int j = 0; j < 64; ++j) acc = fmaf(hs[wid][j], W2[j * 64 + k], acc);
  n_f32[(size_t)node * 64 + k] = acc;
  n_bf[(size_t)node * 64 + k] = (bf16_t)acc;
}

// ---------------- CSR scan + scatter ----------------
__global__ __launch_bounds__(1024) void scan_kernel(const int* __restrict__ counts,
                                                    int* __restrict__ row_ptr,
                                                    int* __restrict__ cursor) {
  __shared__ int sums[1024];
  const int t = threadIdx.x;
  int s = 0;
#pragma unroll 4
  for (int i = 0; i < 32; ++i) s += counts[t * 32 + i];
  sums[t] = s;
  __syncthreads();
#pragma unroll
  for (int d = 1; d < 1024; d <<= 1) {
    int v = (t >= d) ? sums[t - d] : 0;
    __syncthreads();
    sums[t] += v;
    __syncthreads();
  }
  int prefix = sums[t] - s;
  for (int i = 0; i < 32; ++i) {
    int idx = t * 32 + i;
    row_ptr[idx] = prefix;
    cursor[idx] = prefix;
    prefix += counts[idx];
  }
  if (t == 1023) row_ptr[NN] = prefix;
}

__global__ __launch_bounds__(256) void scatter_kernel(const int* __restrict__ recv,
                                                      int* __restrict__ cursor,
                                                      int* __restrict__ col_idx) {
  int idx = blockIdx.x * 256 + threadIdx.x;
#pragma unroll
  for (int q = 0; q < 4; ++q) {
    int ei = q * 262144 + idx;
    int pos = atomicAdd(&cursor[recv[ei]], 1);
    col_idx[pos] = ei;  // CSR position -> original edge id
  }
}

// ---------------- mega edge kernel: MODE 0=encode+round0, 1=mid, 2=round4+decode ----------
template <int MODE>
__global__ __launch_bounds__(512, 4) void edge_update_kernel(
    bf16_t* __restrict__ e, const bf16_t* __restrict__ n_bf,
    const int* __restrict__ col_idx, const int* __restrict__ senders,
    const int* __restrict__ receivers,
    const bf16_t* __restrict__ wfr,   // 48 frags
    const float* __restrict__ beu1, const float* __restrict__ beu2,
    const float* __restrict__ edges_init, const float* __restrict__ norm_p,
    const float* __restrict__ Wee1, const float* __restrict__ bee1,
    const float* __restrict__ bee2,
    const float* __restrict__ bd1, const float* __restrict__ Wd2,
    const float* __restrict__ bd2_p, const float* __restrict__ alpha_p,
    float* __restrict__ out) {
  __shared__ alignas(16) bf16_t wlds[16384];   // W1(24) + W2(8) frags = 32 KB
  __shared__ alignas(16) bf16_t tr[8][16][72]; // per-wave transpose buffer
  __shared__ float bias_lds[128];              // beu1 | beu2
  const int tid = threadIdx.x, lane = tid & 63, wid = tid >> 6;
  const int l15 = lane & 15, lg = lane >> 4;

#pragma unroll
  for (int j = 0; j < 4; ++j)
    reinterpret_cast<bf16x8*>(wlds)[j * 512 + tid] =
        reinterpret_cast<const bf16x8*>(wfr)[j * 512 + tid];
  if (tid < 64) bias_lds[tid] = beu1[tid];
  else if (tid < 128) bias_lds[tid] = beu2[tid - 64];
  __syncthreads();  // only block-wide barrier

  float invn = 0.f;
  if constexpr (MODE == 0) invn = 1.0f / *norm_p;
  float nrm = 0.f, alp = 0.f, b2s = 0.f;
  if constexpr (MODE == 2) { nrm = *norm_p; alp = *alpha_p; b2s = *bd2_p; }

  // XCD-aware block swizzle (gridDim.x % 8 == 0)
  const int nb = gridDim.x, cpx = nb >> 3;
  const int bs = (blockIdx.x & 7) * cpx + (blockIdx.x >> 3);
  const int NWAVE = nb * 8;
  const int NG = NE / 32;

  int o[2], si[2], ri[2];
  bf16x8 pe[2][2];
  float px[2];
  auto prefetch = [&](int g) {
#pragma unroll
    for (int sb = 0; sb < 2; ++sb) {
      int row = g * 32 + sb * 16 + l15;
      int oo = col_idx[row];
      o[sb] = oo;
      si[sb] = senders[oo];
      ri[sb] = receivers[oo];
      if constexpr (MODE == 0) {
        px[sb] = edges_init[oo];
      } else {
        const bf16x8* er = reinterpret_cast<const bf16x8*>(e + (size_t)row * 64);
        pe[sb][0] = __builtin_nontemporal_load(er + lg);
        pe[sb][1] = __builtin_nontemporal_load(er + 4 + lg);
      }
    }
  };

  const int g0 = bs * 8 + wid;
  prefetch(g0);
  for (int g = g0; g < NG; g += NWAVE) {
    int co[2] = {o[0], o[1]}, cs[2] = {si[0], si[1]}, cr[2] = {ri[0], ri[1]};
    bf16x8 ce[2][2];
    float cx[2];
#pragma unroll
    for (int sb = 0; sb < 2; ++sb) {
      if constexpr (MODE == 0) cx[sb] = px[sb];
      else { ce[sb][0] = pe[sb][0]; ce[sb][1] = pe[sb][1]; }
    }
    // issue n gathers for current group
    bf16x8 as_[2][2], ar_[2][2];
#pragma unroll
    for (int sb = 0; sb < 2; ++sb) {
      const bf16x8* sp = reinterpret_cast<const bf16x8*>(n_bf + (size_t)cs[sb] * 64);
      as_[sb][0] = sp[lg];
      as_[sb][1] = sp[4 + lg];
      const bf16x8* rp = reinterpret_cast<const bf16x8*>(n_bf + (size_t)cr[sb] * 64);
      ar_[sb][0] = rp[lg];
      ar_[sb][1] = rp[4 + lg];
    }
    int gn = g + NWAVE;
    if (gn < NG) prefetch(gn);

    if constexpr (MODE == 0) {
      // encoder: h as B-frag directly, then e = h @ Wee2 + bee2, transpose to B-frag
      f32x4 wl0 = *reinterpret_cast<const f32x4*>(Wee1 + lg * 8);
      f32x4 wl1 = *reinterpret_cast<const f32x4*>(Wee1 + lg * 8 + 4);
      f32x4 wh0 = *reinterpret_cast<const f32x4*>(Wee1 + 32 + lg * 8);
      f32x4 wh1 = *reinterpret_cast<const f32x4*>(Wee1 + 32 + lg * 8 + 4);
      f32x4 bl0 = *reinterpret_cast<const f32x4*>(bee1 + lg * 8);
      f32x4 bl1 = *reinterpret_cast<const f32x4*>(bee1 + lg * 8 + 4);
      f32x4 bh0 = *reinterpret_cast<const f32x4*>(bee1 + 32 + lg * 8);
      f32x4 bh1 = *reinterpret_cast<const f32x4*>(bee1 + 32 + lg * 8 + 4);
#pragma unroll
      for (int sb = 0; sb < 2; ++sb) {
        float xv = cx[sb] * invn;
        bf16x8 h0, h1;
#pragma unroll
        for (int i = 0; i < 4; ++i) {
          h0[i]     = (bf16_t)fmaxf(fmaf(xv, wl0[i], bl0[i]), 0.0f);
          h0[4 + i] = (bf16_t)fmaxf(fmaf(xv, wl1[i], bl1[i]), 0.0f);
          h1[i]     = (bf16_t)fmaxf(fmaf(xv, wh0[i], bh0[i]), 0.0f);
          h1[4 + i] = (bf16_t)fmaxf(fmaf(xv, wh1[i], bh1[i]), 0.0f);
        }
        f32x4 ae[4];
#pragma unroll
        for (int nt = 0; nt < 4; ++nt)
          ae[nt] = *reinterpret_cast<const f32x4*>(bee2 + nt * 16 + lg * 4);
#pragma unroll
        for (int kt = 0; kt < 2; ++kt)
#pragma unroll
          for (int nt = 0; nt < 4; ++nt) {
            bf16x8 wf = *reinterpret_cast<const bf16x8*>(
                wfr + (size_t)(32 + kt * 4 + nt) * 512 + lane * 8);
            ae[nt] = __builtin_amdgcn_mfma_f32_16x16x32_bf16(wf, kt ? h1 : h0, ae[nt], 0, 0, 0);
          }
#pragma unroll
        for (int nt = 0; nt < 4; ++nt) {
          bf16x4 pk;
#pragma unroll
          for (int r = 0; r < 4; ++r) pk[r] = (bf16_t)ae[nt][r];
          *reinterpret_cast<bf16x4*>(&tr[wid][l15][nt * 16 + lg * 4]) = pk;
        }
        ce[sb][0] = *reinterpret_cast<const bf16x8*>(&tr[wid][l15][lg * 8]);
        ce[sb][1] = *reinterpret_cast<const bf16x8*>(&tr[wid][l15][32 + lg * 8]);
      }
    }

    // layer 1: both sub-blocks share every W-frag read
    f32x4 acc[2][4];
#pragma unroll
    for (int nt = 0; nt < 4; ++nt) {
      f32x4 bi = *reinterpret_cast<const f32x4*>(&bias_lds[nt * 16 + lg * 4]);
      acc[0][nt] = bi;
      acc[1][nt] = bi;
    }
#pragma unroll
    for (int kt = 0; kt < 6; ++kt) {
#pragma unroll
      for (int nt = 0; nt < 4; ++nt) {
        bf16x8 w = *reinterpret_cast<const bf16x8*>(wlds + (kt * 4 + nt) * 512 + lane * 8);
        bf16x8 m0 = (kt < 2) ? ce[0][kt] : (kt < 4) ? as_[0][kt - 2] : ar_[0][kt - 4];
        bf16x8 m1 = (kt < 2) ? ce[1][kt] : (kt < 4) ? as_[1][kt - 2] : ar_[1][kt - 4];
        acc[0][nt] = __builtin_amdgcn_mfma_f32_16x16x32_bf16(w, m0, acc[0][nt], 0, 0, 0);
        acc[1][nt] = __builtin_amdgcn_mfma_f32_16x16x32_bf16(w, m1, acc[1][nt], 0, 0, 0);
      }
    }
    // relu -> transpose to B-frag (per-sb sequential reuse of tr)
    bf16x8 h[2][2];
#pragma unroll
    for (int sb = 0; sb < 2; ++sb) {
#pragma unroll
      for (int nt = 0; nt < 4; ++nt) {
        bf16x4 pk;
#pragma unroll
        for (int r = 0; r < 4; ++r) pk[r] = (bf16_t)fmaxf(acc[sb][nt][r], 0.0f);
        *reinterpret_cast<bf16x4*>(&tr[wid][l15][nt * 16 + lg * 4]) = pk;
      }
      h[sb][0] = *reinterpret_cast<const bf16x8*>(&tr[wid][l15][lg * 8]);
      h[sb][1] = *reinterpret_cast<const bf16x8*>(&tr[wid][l15][32 + lg * 8]);
    }
    // layer 2
    f32x4 acc2[2][4];
#pragma unroll
    for (int nt = 0; nt < 4; ++nt) {
      f32x4 bi = *reinterpret_cast<const f32x4*>(&bias_lds[64 + nt * 16 + lg * 4]);
      acc2[0][nt] = bi;
      acc2[1][nt] = bi;
    }
#pragma unroll
    for (int kt = 0; kt < 2; ++kt) {
#pragma unroll
      for (int nt = 0; nt < 4; ++nt) {
        bf16x8 w = *reinterpret_cast<const bf16x8*>(wlds + (24 + kt * 4 + nt) * 512 + lane * 8);
        acc2[0][nt] = __builtin_amdgcn_mfma_f32_16x16x32_bf16(w, h[0][kt], acc2[0][nt], 0, 0, 0);
        acc2[1][nt] = __builtin_amdgcn_mfma_f32_16x16x32_bf16(w, h[1][kt], acc2[1][nt], 0, 0, 0);
      }
    }

    if constexpr (MODE == 2) {
      // decoder fused; final e never stored
#pragma unroll
      for (int sb = 0; sb < 2; ++sb) {
#pragma unroll
        for (int nt = 0; nt < 4; ++nt) {
          bf16x4 pk;
#pragma unroll
          for (int r = 0; r < 4; ++r) pk[r] = (bf16_t)acc2[sb][nt][r];
          *reinterpret_cast<bf16x4*>(&tr[wid][l15][nt * 16 + lg * 4]) = pk;
        }
        bf16x8 eb0 = *reinterpret_cast<const bf16x8*>(&tr[wid][l15][lg * 8]);
        bf16x8 eb1 = *reinterpret_cast<const bf16x8*>(&tr[wid][l15][32 + lg * 8]);
        f32x4 ad[4];
#pragma unroll
        for (int nt = 0; nt < 4; ++nt)
          ad[nt] = *reinterpret_cast<const f32x4*>(bd1 + nt * 16 + lg * 4);
#pragma unroll
        for (int kt = 0; kt < 2; ++kt)
#pragma unroll
          for (int nt = 0; nt < 4; ++nt) {
            bf16x8 wf = *reinterpret_cast<const bf16x8*>(
                wfr + (size_t)(40 + kt * 4 + nt) * 512 + lane * 8);
            ad[nt] = __builtin_amdgcn_mfma_f32_16x16x32_bf16(wf, kt ? eb1 : eb0, ad[nt], 0, 0, 0);
          }
        float s = 0.0f;
#pragma unroll
        for (int nt = 0; nt < 4; ++nt) {
          f32x4 w2 = *reinterpret_cast<const f32x4*>(Wd2 + nt * 16 + lg * 4);
#pragma unroll
          for (int r = 0; r < 4; ++r) s = fmaf(fmaxf(ad[nt][r], 0.0f), w2[r], s);
        }
        s += __shfl_xor(s, 16, 64);
        s += __shfl_xor(s, 32, 64);
        float ei = edges_init[co[sb]];
        if (lg == 0) {
          float dv = s + b2s;
          out[co[sb]] = (cr[sb] >= cs[sb]) ? fmaf(alp * nrm, dv, ei) : 0.0f;
        }
      }
    } else {
#pragma unroll
      for (int sb = 0; sb < 2; ++sb) {
        int row = g * 32 + sb * 16 + l15;
#pragma unroll
        for (int nt = 0; nt < 4; ++nt) {
          bf16x4 pk;
#pragma unroll
          for (int r = 0; r < 4; ++r) pk[r] = (bf16_t)acc2[sb][nt][r];
          __builtin_nontemporal_store(
              pk, reinterpret_cast<bf16x4*>(e + (size_t)row * 64 + nt * 16 + lg * 4));
        }
      }
    }
  }
}

// ---------------- node update: chunked coalesced agg + LDS weights ----------------
__global__ __launch_bounds__(256) void node_update_kernel(
    const bf16_t* __restrict__ e, const int* __restrict__ row_ptr,
    const float* __restrict__ Wnu1, const float* __restrict__ bnu1,
    const float* __restrict__ Wnu2, const float* __restrict__ bnu2,
    float* __restrict__ n_f32, bf16_t* __restrict__ n_bf) {
  __shared__ float w1[128 * 64];
  __shared__ float w2[64 * 64];
  __shared__ float xs[4][128];
  __shared__ float hs[4][64];
  const int tid = threadIdx.x, lane = tid & 63, wid = tid >> 6;
#pragma unroll
  for (int j = 0; j < 8; ++j)
    reinterpret_cast<float4*>(w1)[j * 256 + tid] =
        reinterpret_cast<const float4*>(Wnu1)[j * 256 + tid];
#pragma unroll
  for (int j = 0; j < 4; ++j)
    reinterpret_cast<float4*>(w2)[j * 256 + tid] =
        reinterpret_cast<const float4*>(Wnu2)[j * 256 + tid];
  __syncthreads();

  const int rsub = lane >> 3;  // row-within-chunk 0..7 (one chunk = 8 rows = 1024 B)
  for (int tile = blockIdx.x; tile < NN / 4; tile += gridDim.x) {
    const int node = tile * 4 + wid;
    const int p0 = row_ptr[node], cnt = row_ptr[node + 1] - p0;
    float a[8] = {0, 0, 0, 0, 0, 0, 0, 0};
    const bf16_t* base = e + (size_t)p0 * 64;
    const int nchunk = (cnt + 7) >> 3;  // 8 rows (64 lanes x 8 bf16 = 512 elems) per chunk
    for (int c = 0; c < nchunk; ++c) {
      bf16x8 v = __builtin_nontemporal_load(
          reinterpret_cast<const bf16x8*>(base + (size_t)c * 512) + lane);
      if (c * 8 + rsub < cnt) {
#pragma unroll
        for (int i = 0; i < 8; ++i) a[i] += (float)v[i];
      }
    }
#pragma unroll
    for (int i = 0; i < 8; ++i) {  // reduce over rsub (lane bits 3,4,5)
      a[i] += __shfl_xor(a[i], 8, 64);
      a[i] += __shfl_xor(a[i], 16, 64);
      a[i] += __shfl_xor(a[i], 32, 64);
    }
    if (lane < 8) {  // lanes 0..7 (rsub=0) hold hidden dims lane*8+i
#pragma unroll
      for (int i = 0; i < 8; ++i) xs[wid][64 + lane * 8 + i] = a[i];
    }
    xs[wid][lane] = n_f32[(size_t)node * 64 + lane];
    float c0 = bnu1[lane], c1 = 0, c2 = 0, c3 = 0;
#pragma unroll 8
    for (int j = 0; j < 32; ++j) {
      c0 = fmaf(xs[wid][j],      w1[j * 64 + lane],        c0);
      c1 = fmaf(xs[wid][32 + j], w1[(32 + j) * 64 + lane], c1);
      c2 = fmaf(xs[wid][64 + j], w1[(64 + j) * 64 + lane], c2);
      c3 = fmaf(xs[wid][96 + j], w1[(96 + j) * 64 + lane], c3);
    }
    hs[wid][lane] = fmaxf((c0 + c1) + (c2 + c3), 0.0f);
    float d0 = bnu2[lane], d1 = 0;
#pragma unroll 8
    for (int j = 0; j < 32; ++j) {
      d0 = fmaf(hs[wid][j],      w2[j * 64 + lane],        d0);
      d1 = fmaf(hs[wid][32 + j], w2[(32 + j) * 64 + lane], d1);
    }
    float r = d0 + d1;
    n_f32[(size_t)node * 64 + lane] = r;
    n_bf[(size_t)node * 64 + lane] = (bf16_t)r;
  }
}

extern "C" void kernel_launch(void* const* d_in, const int* in_sizes, int n_in,
                              void* d_out, int out_size, void* d_ws, size_t ws_size,
                              hipStream_t stream) {
  const float* nodes      = (const float*)d_in[0];
  const float* edges_init = (const float*)d_in[1];
  const int*   receivers  = (const int*)d_in[2];
  const int*   senders    = (const int*)d_in[3];
  const float* Wne1 = (const float*)d_in[4];
  const float* bne1 = (const float*)d_in[5];
  const float* Wne2 = (const float*)d_in[6];
  const float* bne2 = (const float*)d_in[7];
  const float* Wee1 = (const float*)d_in[8];
  const float* bee1 = (const float*)d_in[9];
  const float* Wee2 = (const float*)d_in[10];
  const float* bee2 = (const float*)d_in[11];
  const float* Weu1 = (const float*)d_in[12];
  const float* beu1 = (const float*)d_in[13];
  const float* Weu2 = (const float*)d_in[14];
  const float* beu2 = (const float*)d_in[15];
  const float* Wnu1 = (const float*)d_in[16];
  const float* bnu1 = (const float*)d_in[17];
  const float* Wnu2 = (const float*)d_in[18];
  const float* bnu2 = (const float*)d_in[19];
  const float* Wd1  = (const float*)d_in[20];
  const float* bd1  = (const float*)d_in[21];
  const float* Wd2  = (const float*)d_in[22];
  const float* bd2  = (const float*)d_in[23];
  const float* alpha = (const float*)d_in[24];
  float* out = (float*)d_out;
  (void)in_sizes; (void)n_in; (void)out_size; (void)ws_size;

  char* ws = (char*)d_ws;
  size_t off = 0;
  auto alloc = [&](size_t bytes) -> void* {
    void* p = ws + off;
    off = (off + bytes + 255) & ~(size_t)255;
    return p;
  };
  float*  norm    = (float*)alloc(4);
  int*    counts  = (int*)alloc(sizeof(int) * NN);
  int*    row_ptr = (int*)alloc(sizeof(int) * (NN + 1));
  int*    cursor  = (int*)alloc(sizeof(int) * (NN + 1));
  int*    col_idx = (int*)alloc(sizeof(int) * NE);
  float*  n_f32   = (float*)alloc(sizeof(float) * (size_t)NN * 64);
  bf16_t* n_bf    = (bf16_t*)alloc(sizeof(bf16_t) * (size_t)NN * 64);
  bf16_t* e_buf   = (bf16_t*)alloc(sizeof(bf16_t) * (size_t)NE * 64 + 1024);  // +pad: node_update tail overread (<=896B)
  bf16_t* wfr     = (bf16_t*)alloc(sizeof(bf16_t) * 48 * 512);

  hipMemsetAsync(norm, 0, 4, stream);
  hipMemsetAsync(counts, 0, sizeof(int) * NN, stream);

  stats_kernel<<<1024, 256, 0, stream>>>(edges_init, receivers, norm, counts);
  prep_all_kernel<<<96, 256, 0, stream>>>(Weu1, Weu2, Wee2, Wd1, wfr);
  node_encode_kernel<<<NN / 4, 256, 0, stream>>>(nodes, Wne1, bne1, Wne2, bne2, n_f32, n_bf);
  scan_kernel<<<1, 1024, 0, stream>>>(counts, row_ptr, cursor);
  scatter_kernel<<<1024, 256, 0, stream>>>(receivers, cursor, col_idx);

  edge_update_kernel<0><<<1024, 512, 0, stream>>>(
      e_buf, n_bf, col_idx, senders, receivers, wfr, beu1, beu2,
      edges_init, norm, Wee1, bee1, bee2, bd1, Wd2, bd2, alpha, out);
  for (int t = 1; t <= 4; ++t) {
    node_update_kernel<<<2048, 256, 0, stream>>>(e_buf, row_ptr,
                                                 Wnu1, bnu1, Wnu2, bnu2, n_f32, n_bf);
    if (t < 4)
      edge_update_kernel<1><<<1024, 512, 0, stream>>>(
          e_buf, n_bf, col_idx, senders, receivers, wfr, beu1, beu2,
          edges_init, norm, Wee1, bee1, bee2, bd1, Wd2, bd2, alpha, out);
    else
      edge_update_kernel<2><<<1024, 512, 0, stream>>>(
          e_buf, n_bf, col_idx, senders, receivers, wfr, beu1, beu2,
          edges_init, norm, Wee1, bee1, bee2, bd1, Wd2, bd2, alpha, out);
  }
}

// Round 5
// 1157.776 us; speedup vs baseline: 2.5675x; 2.5675x over previous
//
#include <hip/hip_runtime.h>

#define NN 32768
#define NE 1048576

typedef __bf16 bf16_t;
typedef __bf16 bf16x8 __attribute__((ext_vector_type(8)));
typedef __bf16 bf16x4 __attribute__((ext_vector_type(4)));
typedef float f32x4 __attribute__((ext_vector_type(4)));

// ---------------- absmax(edges_init) + receiver counts (fused) ----------------
__global__ __launch_bounds__(256) void stats_kernel(const float* __restrict__ x,
                                                    const int* __restrict__ recv,
                                                    float* __restrict__ norm,
                                                    int* __restrict__ counts) {
  int idx = blockIdx.x * 256 + threadIdx.x;
  float4 v = reinterpret_cast<const float4*>(x)[idx];
  float m = fmaxf(fmaxf(fabsf(v.x), fabsf(v.y)), fmaxf(fabsf(v.z), fabsf(v.w)));
#pragma unroll
  for (int off = 32; off > 0; off >>= 1) m = fmaxf(m, __shfl_xor(m, off, 64));
  if ((threadIdx.x & 63) == 0)
    atomicMax(reinterpret_cast<unsigned int*>(norm), __float_as_uint(m));
  int4 r = reinterpret_cast<const int4*>(recv)[idx];
  atomicAdd(&counts[r.x], 1);
  atomicAdd(&counts[r.y], 1);
  atomicAdd(&counts[r.z], 1);
  atomicAdd(&counts[r.w], 1);
}

// ---------------- all weights -> bf16 fragment layout, one buffer ----------------
// frag f: lane l holds W[k = kt*32 + (l>>4)*8 + i][col = nt*16 + (l&15)], i=0..7
// layout: [Weu1: f 0-23][Weu2: 24-31][Wee2: 32-39][Wd1: 40-47]
__global__ __launch_bounds__(256) void prep_all_kernel(const float* __restrict__ Weu1,
                                                       const float* __restrict__ Weu2,
                                                       const float* __restrict__ Wee2,
                                                       const float* __restrict__ Wd1,
                                                       bf16_t* __restrict__ dst) {
  int idx = blockIdx.x * 256 + threadIdx.x;  // 48*512 = 24576 total
  int i = idx & 7, lane = (idx >> 3) & 63, f = idx >> 9;
  const float* W;
  int fl;
  if (f < 24)      { W = Weu1; fl = f; }
  else if (f < 32) { W = Weu2; fl = f - 24; }
  else if (f < 40) { W = Wee2; fl = f - 32; }
  else             { W = Wd1;  fl = f - 40; }
  int kt = fl >> 2, nt = fl & 3;
  int k = kt * 32 + ((lane >> 4) << 3) + i;
  int col = nt * 16 + (lane & 15);
  dst[idx] = (bf16_t)W[k * 64 + col];
}

// ---------------- node encoder (fp32, exact) ----------------
__global__ __launch_bounds__(256) void node_encode_kernel(
    const float* __restrict__ nodes, const float* __restrict__ W1, const float* __restrict__ b1,
    const float* __restrict__ W2, const float* __restrict__ b2,
    float* __restrict__ n_f32, bf16_t* __restrict__ n_bf) {
  __shared__ float hs[4][64];
  int wid = threadIdx.x >> 6, k = threadIdx.x & 63;
  int node = blockIdx.x * 4 + wid;
  float x = nodes[node];
  hs[wid][k] = fmaxf(x * W1[k] + b1[k], 0.0f);
  __syncthreads();
  float acc = b2[k];
#pragma unroll 8
  for (int j = 0; j < 64; ++j) acc = fmaf(hs[wid][j], W2[j * 64 + k], acc);
  n_f32[(size_t)node * 64 + k] = acc;
  n_bf[(size_t)node * 64 + k] = (bf16_t)acc;
}

// ---------------- CSR scan + scatter ----------------
__global__ __launch_bounds__(1024) void scan_kernel(const int* __restrict__ counts,
                                                    int* __restrict__ row_ptr,
                                                    int* __restrict__ cursor) {
  __shared__ int sums[1024];
  const int t = threadIdx.x;
  int s = 0;
#pragma unroll 4
  for (int i = 0; i < 32; ++i) s += counts[t * 32 + i];
  sums[t] = s;
  __syncthreads();
#pragma unroll
  for (int d = 1; d < 1024; d <<= 1) {
    int v = (t >= d) ? sums[t - d] : 0;
    __syncthreads();
    sums[t] += v;
    __syncthreads();
  }
  int prefix = sums[t] - s;
  for (int i = 0; i < 32; ++i) {
    int idx = t * 32 + i;
    row_ptr[idx] = prefix;
    cursor[idx] = prefix;
    prefix += counts[idx];
  }
  if (t == 1023) row_ptr[NN] = prefix;
}

__global__ __launch_bounds__(256) void scatter_kernel(const int* __restrict__ recv,
                                                      int* __restrict__ cursor,
                                                      int* __restrict__ col_idx) {
  int idx = blockIdx.x * 256 + threadIdx.x;
#pragma unroll
  for (int q = 0; q < 4; ++q) {
    int ei = q * 262144 + idx;
    int pos = atomicAdd(&cursor[recv[ei]], 1);
    col_idx[pos] = ei;  // CSR position -> original edge id
  }
}

// ---------------- mega edge kernel: MODE 0=encode+round0, 1=mid, 2=round4+decode ----------
// 256 threads, NO min-wave clamp: R4's __launch_bounds__(512,4) starved the kernel to
// 64 VGPRs -> 2.4 GB scratch spill traffic. Live state needs ~150 VGPRs (Guideline 6).
template <int MODE>
__global__ __launch_bounds__(256) void edge_update_kernel(
    bf16_t* __restrict__ e, const bf16_t* __restrict__ n_bf,
    const int* __restrict__ col_idx, const int* __restrict__ senders,
    const int* __restrict__ receivers,
    const bf16_t* __restrict__ wfr,   // 48 frags
    const float* __restrict__ beu1, const float* __restrict__ beu2,
    const float* __restrict__ edges_init, const float* __restrict__ norm_p,
    const float* __restrict__ Wee1, const float* __restrict__ bee1,
    const float* __restrict__ bee2,
    const float* __restrict__ bd1, const float* __restrict__ Wd2,
    const float* __restrict__ bd2_p, const float* __restrict__ alpha_p,
    float* __restrict__ out) {
  __shared__ alignas(16) bf16_t wlds[16384];   // W1(24) + W2(8) frags = 32 KB
  __shared__ alignas(16) bf16_t tr[4][16][72]; // per-wave transpose buffer
  __shared__ float bias_lds[128];              // beu1 | beu2
  const int tid = threadIdx.x, lane = tid & 63, wid = tid >> 6;
  const int l15 = lane & 15, lg = lane >> 4;

#pragma unroll
  for (int j = 0; j < 8; ++j)
    reinterpret_cast<bf16x8*>(wlds)[j * 256 + tid] =
        reinterpret_cast<const bf16x8*>(wfr)[j * 256 + tid];
  if (tid < 64) bias_lds[tid] = beu1[tid];
  else if (tid < 128) bias_lds[tid] = beu2[tid - 64];
  __syncthreads();  // only block-wide barrier

  float invn = 0.f;
  if constexpr (MODE == 0) invn = 1.0f / *norm_p;
  float nrm = 0.f, alp = 0.f, b2s = 0.f;
  if constexpr (MODE == 2) { nrm = *norm_p; alp = *alpha_p; b2s = *bd2_p; }

  // XCD-aware block swizzle (gridDim.x % 8 == 0)
  const int nb = gridDim.x, cpx = nb >> 3;
  const int bs = (blockIdx.x & 7) * cpx + (blockIdx.x >> 3);
  const int NWAVE = nb * 4;
  const int NG = NE / 32;

  int o[2], si[2], ri[2];
  bf16x8 pe[2][2];
  float px[2];
  auto prefetch = [&](int g) {
#pragma unroll
    for (int sb = 0; sb < 2; ++sb) {
      int row = g * 32 + sb * 16 + l15;
      int oo = col_idx[row];
      o[sb] = oo;
      si[sb] = senders[oo];
      ri[sb] = receivers[oo];
      if constexpr (MODE == 0) {
        px[sb] = edges_init[oo];
      } else {
        const bf16x8* er = reinterpret_cast<const bf16x8*>(e + (size_t)row * 64);
        pe[sb][0] = __builtin_nontemporal_load(er + lg);
        pe[sb][1] = __builtin_nontemporal_load(er + 4 + lg);
      }
    }
  };

  const int g0 = bs * 4 + wid;
  prefetch(g0);
  for (int g = g0; g < NG; g += NWAVE) {
    int co[2] = {o[0], o[1]}, cs[2] = {si[0], si[1]}, cr[2] = {ri[0], ri[1]};
    bf16x8 ce[2][2];
    float cx[2];
#pragma unroll
    for (int sb = 0; sb < 2; ++sb) {
      if constexpr (MODE == 0) cx[sb] = px[sb];
      else { ce[sb][0] = pe[sb][0]; ce[sb][1] = pe[sb][1]; }
    }
    // issue n gathers for current group
    bf16x8 as_[2][2], ar_[2][2];
#pragma unroll
    for (int sb = 0; sb < 2; ++sb) {
      const bf16x8* sp = reinterpret_cast<const bf16x8*>(n_bf + (size_t)cs[sb] * 64);
      as_[sb][0] = sp[lg];
      as_[sb][1] = sp[4 + lg];
      const bf16x8* rp = reinterpret_cast<const bf16x8*>(n_bf + (size_t)cr[sb] * 64);
      ar_[sb][0] = rp[lg];
      ar_[sb][1] = rp[4 + lg];
    }
    int gn = g + NWAVE;
    if (gn < NG) prefetch(gn);

    if constexpr (MODE == 0) {
      // encoder: h as B-frag directly, then e = h @ Wee2 + bee2, transpose to B-frag
      f32x4 wl0 = *reinterpret_cast<const f32x4*>(Wee1 + lg * 8);
      f32x4 wl1 = *reinterpret_cast<const f32x4*>(Wee1 + lg * 8 + 4);
      f32x4 wh0 = *reinterpret_cast<const f32x4*>(Wee1 + 32 + lg * 8);
      f32x4 wh1 = *reinterpret_cast<const f32x4*>(Wee1 + 32 + lg * 8 + 4);
      f32x4 bl0 = *reinterpret_cast<const f32x4*>(bee1 + lg * 8);
      f32x4 bl1 = *reinterpret_cast<const f32x4*>(bee1 + lg * 8 + 4);
      f32x4 bh0 = *reinterpret_cast<const f32x4*>(bee1 + 32 + lg * 8);
      f32x4 bh1 = *reinterpret_cast<const f32x4*>(bee1 + 32 + lg * 8 + 4);
#pragma unroll
      for (int sb = 0; sb < 2; ++sb) {
        float xv = cx[sb] * invn;
        bf16x8 h0, h1;
#pragma unroll
        for (int i = 0; i < 4; ++i) {
          h0[i]     = (bf16_t)fmaxf(fmaf(xv, wl0[i], bl0[i]), 0.0f);
          h0[4 + i] = (bf16_t)fmaxf(fmaf(xv, wl1[i], bl1[i]), 0.0f);
          h1[i]     = (bf16_t)fmaxf(fmaf(xv, wh0[i], bh0[i]), 0.0f);
          h1[4 + i] = (bf16_t)fmaxf(fmaf(xv, wh1[i], bh1[i]), 0.0f);
        }
        f32x4 ae[4];
#pragma unroll
        for (int nt = 0; nt < 4; ++nt)
          ae[nt] = *reinterpret_cast<const f32x4*>(bee2 + nt * 16 + lg * 4);
#pragma unroll
        for (int kt = 0; kt < 2; ++kt)
#pragma unroll
          for (int nt = 0; nt < 4; ++nt) {
            bf16x8 wf = *reinterpret_cast<const bf16x8*>(
                wfr + (size_t)(32 + kt * 4 + nt) * 512 + lane * 8);
            ae[nt] = __builtin_amdgcn_mfma_f32_16x16x32_bf16(wf, kt ? h1 : h0, ae[nt], 0, 0, 0);
          }
#pragma unroll
        for (int nt = 0; nt < 4; ++nt) {
          bf16x4 pk;
#pragma unroll
          for (int r = 0; r < 4; ++r) pk[r] = (bf16_t)ae[nt][r];
          *reinterpret_cast<bf16x4*>(&tr[wid][l15][nt * 16 + lg * 4]) = pk;
        }
        ce[sb][0] = *reinterpret_cast<const bf16x8*>(&tr[wid][l15][lg * 8]);
        ce[sb][1] = *reinterpret_cast<const bf16x8*>(&tr[wid][l15][32 + lg * 8]);
      }
    }

    // layer 1: both sub-blocks share every W-frag read
    f32x4 acc[2][4];
#pragma unroll
    for (int nt = 0; nt < 4; ++nt) {
      f32x4 bi = *reinterpret_cast<const f32x4*>(&bias_lds[nt * 16 + lg * 4]);
      acc[0][nt] = bi;
      acc[1][nt] = bi;
    }
#pragma unroll
    for (int kt = 0; kt < 6; ++kt) {
#pragma unroll
      for (int nt = 0; nt < 4; ++nt) {
        bf16x8 w = *reinterpret_cast<const bf16x8*>(wlds + (kt * 4 + nt) * 512 + lane * 8);
        bf16x8 m0 = (kt < 2) ? ce[0][kt] : (kt < 4) ? as_[0][kt - 2] : ar_[0][kt - 4];
        bf16x8 m1 = (kt < 2) ? ce[1][kt] : (kt < 4) ? as_[1][kt - 2] : ar_[1][kt - 4];
        acc[0][nt] = __builtin_amdgcn_mfma_f32_16x16x32_bf16(w, m0, acc[0][nt], 0, 0, 0);
        acc[1][nt] = __builtin_amdgcn_mfma_f32_16x16x32_bf16(w, m1, acc[1][nt], 0, 0, 0);
      }
    }
    // relu -> transpose to B-frag (per-sb sequential reuse of tr)
    bf16x8 h[2][2];
#pragma unroll
    for (int sb = 0; sb < 2; ++sb) {
#pragma unroll
      for (int nt = 0; nt < 4; ++nt) {
        bf16x4 pk;
#pragma unroll
        for (int r = 0; r < 4; ++r) pk[r] = (bf16_t)fmaxf(acc[sb][nt][r], 0.0f);
        *reinterpret_cast<bf16x4*>(&tr[wid][l15][nt * 16 + lg * 4]) = pk;
      }
      h[sb][0] = *reinterpret_cast<const bf16x8*>(&tr[wid][l15][lg * 8]);
      h[sb][1] = *reinterpret_cast<const bf16x8*>(&tr[wid][l15][32 + lg * 8]);
    }
    // layer 2
    f32x4 acc2[2][4];
#pragma unroll
    for (int nt = 0; nt < 4; ++nt) {
      f32x4 bi = *reinterpret_cast<const f32x4*>(&bias_lds[64 + nt * 16 + lg * 4]);
      acc2[0][nt] = bi;
      acc2[1][nt] = bi;
    }
#pragma unroll
    for (int kt = 0; kt < 2; ++kt) {
#pragma unroll
      for (int nt = 0; nt < 4; ++nt) {
        bf16x8 w = *reinterpret_cast<const bf16x8*>(wlds + (24 + kt * 4 + nt) * 512 + lane * 8);
        acc2[0][nt] = __builtin_amdgcn_mfma_f32_16x16x32_bf16(w, h[0][kt], acc2[0][nt], 0, 0, 0);
        acc2[1][nt] = __builtin_amdgcn_mfma_f32_16x16x32_bf16(w, h[1][kt], acc2[1][nt], 0, 0, 0);
      }
    }

    if constexpr (MODE == 2) {
      // decoder fused; final e never stored
#pragma unroll
      for (int sb = 0; sb < 2; ++sb) {
#pragma unroll
        for (int nt = 0; nt < 4; ++nt) {
          bf16x4 pk;
#pragma unroll
          for (int r = 0; r < 4; ++r) pk[r] = (bf16_t)acc2[sb][nt][r];
          *reinterpret_cast<bf16x4*>(&tr[wid][l15][nt * 16 + lg * 4]) = pk;
        }
        bf16x8 eb0 = *reinterpret_cast<const bf16x8*>(&tr[wid][l15][lg * 8]);
        bf16x8 eb1 = *reinterpret_cast<const bf16x8*>(&tr[wid][l15][32 + lg * 8]);
        f32x4 ad[4];
#pragma unroll
        for (int nt = 0; nt < 4; ++nt)
          ad[nt] = *reinterpret_cast<const f32x4*>(bd1 + nt * 16 + lg * 4);
#pragma unroll
        for (int kt = 0; kt < 2; ++kt)
#pragma unroll
          for (int nt = 0; nt < 4; ++nt) {
            bf16x8 wf = *reinterpret_cast<const bf16x8*>(
                wfr + (size_t)(40 + kt * 4 + nt) * 512 + lane * 8);
            ad[nt] = __builtin_amdgcn_mfma_f32_16x16x32_bf16(wf, kt ? eb1 : eb0, ad[nt], 0, 0, 0);
          }
        float s = 0.0f;
#pragma unroll
        for (int nt = 0; nt < 4; ++nt) {
          f32x4 w2 = *reinterpret_cast<const f32x4*>(Wd2 + nt * 16 + lg * 4);
#pragma unroll
          for (int r = 0; r < 4; ++r) s = fmaf(fmaxf(ad[nt][r], 0.0f), w2[r], s);
        }
        s += __shfl_xor(s, 16, 64);
        s += __shfl_xor(s, 32, 64);
        float ei = edges_init[co[sb]];
        if (lg == 0) {
          float dv = s + b2s;
          out[co[sb]] = (cr[sb] >= cs[sb]) ? fmaf(alp * nrm, dv, ei) : 0.0f;
        }
      }
    } else {
#pragma unroll
      for (int sb = 0; sb < 2; ++sb) {
        int row = g * 32 + sb * 16 + l15;
#pragma unroll
        for (int nt = 0; nt < 4; ++nt) {
          bf16x4 pk;
#pragma unroll
          for (int r = 0; r < 4; ++r) pk[r] = (bf16_t)acc2[sb][nt][r];
          __builtin_nontemporal_store(
              pk, reinterpret_cast<bf16x4*>(e + (size_t)row * 64 + nt * 16 + lg * 4));
        }
      }
    }
  }
}

// ---------------- node update: chunked coalesced agg + LDS weights ----------------
__global__ __launch_bounds__(256) void node_update_kernel(
    const bf16_t* __restrict__ e, const int* __restrict__ row_ptr,
    const float* __restrict__ Wnu1, const float* __restrict__ bnu1,
    const float* __restrict__ Wnu2, const float* __restrict__ bnu2,
    float* __restrict__ n_f32, bf16_t* __restrict__ n_bf) {
  __shared__ float w1[128 * 64];
  __shared__ float w2[64 * 64];
  __shared__ float xs[4][128];
  __shared__ float hs[4][64];
  const int tid = threadIdx.x, lane = tid & 63, wid = tid >> 6;
#pragma unroll
  for (int j = 0; j < 8; ++j)
    reinterpret_cast<float4*>(w1)[j * 256 + tid] =
        reinterpret_cast<const float4*>(Wnu1)[j * 256 + tid];
#pragma unroll
  for (int j = 0; j < 4; ++j)
    reinterpret_cast<float4*>(w2)[j * 256 + tid] =
        reinterpret_cast<const float4*>(Wnu2)[j * 256 + tid];
  __syncthreads();

  const int rsub = lane >> 3;  // row-within-chunk 0..7 (one chunk = 8 rows = 1024 B)
  for (int tile = blockIdx.x; tile < NN / 4; tile += gridDim.x) {
    const int node = tile * 4 + wid;
    const int p0 = row_ptr[node], cnt = row_ptr[node + 1] - p0;
    float a[8] = {0, 0, 0, 0, 0, 0, 0, 0};
    const bf16_t* base = e + (size_t)p0 * 64;
    const int nchunk = (cnt + 7) >> 3;  // 8 rows (64 lanes x 8 bf16 = 512 elems) per chunk
    for (int c = 0; c < nchunk; ++c) {
      bf16x8 v = __builtin_nontemporal_load(
          reinterpret_cast<const bf16x8*>(base + (size_t)c * 512) + lane);
      if (c * 8 + rsub < cnt) {
#pragma unroll
        for (int i = 0; i < 8; ++i) a[i] += (float)v[i];
      }
    }
#pragma unroll
    for (int i = 0; i < 8; ++i) {  // reduce over rsub (lane bits 3,4,5)
      a[i] += __shfl_xor(a[i], 8, 64);
      a[i] += __shfl_xor(a[i], 16, 64);
      a[i] += __shfl_xor(a[i], 32, 64);
    }
    if (lane < 8) {  // lanes 0..7 (rsub=0) hold hidden dims lane*8+i
#pragma unroll
      for (int i = 0; i < 8; ++i) xs[wid][64 + lane * 8 + i] = a[i];
    }
    xs[wid][lane] = n_f32[(size_t)node * 64 + lane];
    float c0 = bnu1[lane], c1 = 0, c2 = 0, c3 = 0;
#pragma unroll 8
    for (int j = 0; j < 32; ++j) {
      c0 = fmaf(xs[wid][j],      w1[j * 64 + lane],        c0);
      c1 = fmaf(xs[wid][32 + j], w1[(32 + j) * 64 + lane], c1);
      c2 = fmaf(xs[wid][64 + j], w1[(64 + j) * 64 + lane], c2);
      c3 = fmaf(xs[wid][96 + j], w1[(96 + j) * 64 + lane], c3);
    }
    hs[wid][lane] = fmaxf((c0 + c1) + (c2 + c3), 0.0f);
    float d0 = bnu2[lane], d1 = 0;
#pragma unroll 8
    for (int j = 0; j < 32; ++j) {
      d0 = fmaf(hs[wid][j],      w2[j * 64 + lane],        d0);
      d1 = fmaf(hs[wid][32 + j], w2[(32 + j) * 64 + lane], d1);
    }
    float r = d0 + d1;
    n_f32[(size_t)node * 64 + lane] = r;
    n_bf[(size_t)node * 64 + lane] = (bf16_t)r;
  }
}

extern "C" void kernel_launch(void* const* d_in, const int* in_sizes, int n_in,
                              void* d_out, int out_size, void* d_ws, size_t ws_size,
                              hipStream_t stream) {
  const float* nodes      = (const float*)d_in[0];
  const float* edges_init = (const float*)d_in[1];
  const int*   receivers  = (const int*)d_in[2];
  const int*   senders    = (const int*)d_in[3];
  const float* Wne1 = (const float*)d_in[4];
  const float* bne1 = (const float*)d_in[5];
  const float* Wne2 = (const float*)d_in[6];
  const float* bne2 = (const float*)d_in[7];
  const float* Wee1 = (const float*)d_in[8];
  const float* bee1 = (const float*)d_in[9];
  const float* Wee2 = (const float*)d_in[10];
  const float* bee2 = (const float*)d_in[11];
  const float* Weu1 = (const float*)d_in[12];
  const float* beu1 = (const float*)d_in[13];
  const float* Weu2 = (const float*)d_in[14];
  const float* beu2 = (const float*)d_in[15];
  const float* Wnu1 = (const float*)d_in[16];
  const float* bnu1 = (const float*)d_in[17];
  const float* Wnu2 = (const float*)d_in[18];
  const float* bnu2 = (const float*)d_in[19];
  const float* Wd1  = (const float*)d_in[20];
  const float* bd1  = (const float*)d_in[21];
  const float* Wd2  = (const float*)d_in[22];
  const float* bd2  = (const float*)d_in[23];
  const float* alpha = (const float*)d_in[24];
  float* out = (float*)d_out;
  (void)in_sizes; (void)n_in; (void)out_size; (void)ws_size;

  char* ws = (char*)d_ws;
  size_t off = 0;
  auto alloc = [&](size_t bytes) -> void* {
    void* p = ws + off;
    off = (off + bytes + 255) & ~(size_t)255;
    return p;
  };
  float*  norm    = (float*)alloc(4);
  int*    counts  = (int*)alloc(sizeof(int) * NN);
  int*    row_ptr = (int*)alloc(sizeof(int) * (NN + 1));
  int*    cursor  = (int*)alloc(sizeof(int) * (NN + 1));
  int*    col_idx = (int*)alloc(sizeof(int) * NE);
  float*  n_f32   = (float*)alloc(sizeof(float) * (size_t)NN * 64);
  bf16_t* n_bf    = (bf16_t*)alloc(sizeof(bf16_t) * (size_t)NN * 64);
  bf16_t* e_buf   = (bf16_t*)alloc(sizeof(bf16_t) * (size_t)NE * 64 + 1024);  // +pad: node_update tail overread (<=896B)
  bf16_t* wfr     = (bf16_t*)alloc(sizeof(bf16_t) * 48 * 512);

  hipMemsetAsync(norm, 0, 4, stream);
  hipMemsetAsync(counts, 0, sizeof(int) * NN, stream);

  stats_kernel<<<1024, 256, 0, stream>>>(edges_init, receivers, norm, counts);
  prep_all_kernel<<<96, 256, 0, stream>>>(Weu1, Weu2, Wee2, Wd1, wfr);
  node_encode_kernel<<<NN / 4, 256, 0, stream>>>(nodes, Wne1, bne1, Wne2, bne2, n_f32, n_bf);
  scan_kernel<<<1, 1024, 0, stream>>>(counts, row_ptr, cursor);
  scatter_kernel<<<1024, 256, 0, stream>>>(receivers, cursor, col_idx);

  edge_update_kernel<0><<<2048, 256, 0, stream>>>(
      e_buf, n_bf, col_idx, senders, receivers, wfr, beu1, beu2,
      edges_init, norm, Wee1, bee1, bee2, bd1, Wd2, bd2, alpha, out);
  for (int t = 1; t <= 4; ++t) {
    node_update_kernel<<<2048, 256, 0, stream>>>(e_buf, row_ptr,
                                                 Wnu1, bnu1, Wnu2, bnu2, n_f32, n_bf);
    if (t < 4)
      edge_update_kernel<1><<<2048, 256, 0, stream>>>(
          e_buf, n_bf, col_idx, senders, receivers, wfr, beu1, beu2,
          edges_init, norm, Wee1, bee1, bee2, bd1, Wd2, bd2, alpha, out);
    else
      edge_update_kernel<2><<<2048, 256, 0, stream>>>(
          e_buf, n_bf, col_idx, senders, receivers, wfr, beu1, beu2,
          edges_init, norm, Wee1, bee1, bee2, bd1, Wd2, bd2, alpha, out);
  }
}

// Round 6
// 1043.955 us; speedup vs baseline: 2.8475x; 1.1090x over previous
//
#include <hip/hip_runtime.h>

#define NN 32768
#define NE 1048576

typedef __bf16 bf16_t;
typedef __bf16 bf16x8 __attribute__((ext_vector_type(8)));
typedef __bf16 bf16x4 __attribute__((ext_vector_type(4)));
typedef float f32x4 __attribute__((ext_vector_type(4)));

// ---------------- absmax(edges_init) + receiver counts (fused) ----------------
__global__ __launch_bounds__(256) void stats_kernel(const float* __restrict__ x,
                                                    const int* __restrict__ recv,
                                                    float* __restrict__ norm,
                                                    int* __restrict__ counts) {
  int idx = blockIdx.x * 256 + threadIdx.x;
  float4 v = reinterpret_cast<const float4*>(x)[idx];
  float m = fmaxf(fmaxf(fabsf(v.x), fabsf(v.y)), fmaxf(fabsf(v.z), fabsf(v.w)));
#pragma unroll
  for (int off = 32; off > 0; off >>= 1) m = fmaxf(m, __shfl_xor(m, off, 64));
  if ((threadIdx.x & 63) == 0)
    atomicMax(reinterpret_cast<unsigned int*>(norm), __float_as_uint(m));
  int4 r = reinterpret_cast<const int4*>(recv)[idx];
  atomicAdd(&counts[r.x], 1);
  atomicAdd(&counts[r.y], 1);
  atomicAdd(&counts[r.z], 1);
  atomicAdd(&counts[r.w], 1);
}

// ---------------- all weights -> bf16 fragment layout, one buffer ----------------
// frag f: lane l holds W[k = kt*32 + (l>>4)*8 + i][col = nt*16 + (l&15)], i=0..7
// layout: [Weu1: f 0-23][Weu2: 24-31][Wee2: 32-39][Wd1: 40-47]
__global__ __launch_bounds__(256) void prep_all_kernel(const float* __restrict__ Weu1,
                                                       const float* __restrict__ Weu2,
                                                       const float* __restrict__ Wee2,
                                                       const float* __restrict__ Wd1,
                                                       bf16_t* __restrict__ dst) {
  int idx = blockIdx.x * 256 + threadIdx.x;  // 48*512 = 24576 total
  int i = idx & 7, lane = (idx >> 3) & 63, f = idx >> 9;
  const float* W;
  int fl;
  if (f < 24)      { W = Weu1; fl = f; }
  else if (f < 32) { W = Weu2; fl = f - 24; }
  else if (f < 40) { W = Wee2; fl = f - 32; }
  else             { W = Wd1;  fl = f - 40; }
  int kt = fl >> 2, nt = fl & 3;
  int k = kt * 32 + ((lane >> 4) << 3) + i;
  int col = nt * 16 + (lane & 15);
  dst[idx] = (bf16_t)W[k * 64 + col];
}

// ---------------- node encoder (fp32, exact) ----------------
__global__ __launch_bounds__(256) void node_encode_kernel(
    const float* __restrict__ nodes, const float* __restrict__ W1, const float* __restrict__ b1,
    const float* __restrict__ W2, const float* __restrict__ b2,
    float* __restrict__ n_f32, bf16_t* __restrict__ n_bf) {
  __shared__ float hs[4][64];
  int wid = threadIdx.x >> 6, k = threadIdx.x & 63;
  int node = blockIdx.x * 4 + wid;
  float x = nodes[node];
  hs[wid][k] = fmaxf(x * W1[k] + b1[k], 0.0f);
  __syncthreads();
  float acc = b2[k];
#pragma unroll 8
  for (int j = 0; j < 64; ++j) acc = fmaf(hs[wid][j], W2[j * 64 + k], acc);
  n_f32[(size_t)node * 64 + k] = acc;
  n_bf[(size_t)node * 64 + k] = (bf16_t)acc;
}

// ---------------- CSR scan + scatter ----------------
__global__ __launch_bounds__(1024) void scan_kernel(const int* __restrict__ counts,
                                                    int* __restrict__ row_ptr,
                                                    int* __restrict__ cursor) {
  __shared__ int sums[1024];
  const int t = threadIdx.x;
  int s = 0;
#pragma unroll 4
  for (int i = 0; i < 32; ++i) s += counts[t * 32 + i];
  sums[t] = s;
  __syncthreads();
#pragma unroll
  for (int d = 1; d < 1024; d <<= 1) {
    int v = (t >= d) ? sums[t - d] : 0;
    __syncthreads();
    sums[t] += v;
    __syncthreads();
  }
  int prefix = sums[t] - s;
  for (int i = 0; i < 32; ++i) {
    int idx = t * 32 + i;
    row_ptr[idx] = prefix;
    cursor[idx] = prefix;
    prefix += counts[idx];
  }
  if (t == 1023) row_ptr[NN] = prefix;
}

__global__ __launch_bounds__(256) void scatter_kernel(const int* __restrict__ recv,
                                                      int* __restrict__ cursor,
                                                      int* __restrict__ col_idx) {
  int idx = blockIdx.x * 256 + threadIdx.x;
#pragma unroll
  for (int q = 0; q < 4; ++q) {
    int ei = q * 262144 + idx;
    int pos = atomicAdd(&cursor[recv[ei]], 1);
    col_idx[pos] = ei;  // CSR position -> original edge id
  }
}

// ---------------- mega edge kernel: MODE 0=encode+round0, 1=mid, 2=round4+decode ----------
// Weu1+Weu2 live in 128 VGPRs (loaded once; all frag indices compile-time after unroll).
// LDS only holds the per-wave h-transpose (+8KB mode-specific W stage) -> LDS pipe no
// longer the bottleneck (was 32KB/group of W ds_reads in R5 = ~2000 clk/CU-iter).
template <int MODE>
__global__ __launch_bounds__(256) void edge_update_kernel(
    bf16_t* __restrict__ e, const bf16_t* __restrict__ n_bf,
    const int* __restrict__ col_idx, const int* __restrict__ senders,
    const int* __restrict__ receivers,
    const bf16_t* __restrict__ wfr,   // 48 frags
    const float* __restrict__ beu1, const float* __restrict__ beu2,
    const float* __restrict__ edges_init, const float* __restrict__ norm_p,
    const float* __restrict__ Wee1, const float* __restrict__ bee1,
    const float* __restrict__ bee2,
    const float* __restrict__ bd1, const float* __restrict__ Wd2,
    const float* __restrict__ bd2_p, const float* __restrict__ alpha_p,
    float* __restrict__ out) {
  __shared__ alignas(16) bf16_t tr[4][16][72];  // per-wave transpose buffer
  __shared__ alignas(16) bf16_t wstage[4096];   // Wee2 (MODE0) / Wd1 (MODE2) frags
  const int tid = threadIdx.x, lane = tid & 63, wid = tid >> 6;
  const int l15 = lane & 15, lg = lane >> 4;

  // Weu1 (24 frags) + Weu2 (8 frags) -> registers, once
  bf16x8 W1r[24], W2r[8];
#pragma unroll
  for (int f = 0; f < 24; ++f)
    W1r[f] = *reinterpret_cast<const bf16x8*>(wfr + (size_t)f * 512 + lane * 8);
#pragma unroll
  for (int f = 0; f < 8; ++f)
    W2r[f] = *reinterpret_cast<const bf16x8*>(wfr + (size_t)(24 + f) * 512 + lane * 8);

  if constexpr (MODE == 0 || MODE == 2) {
    const int fb = (MODE == 0) ? 32 : 40;
#pragma unroll
    for (int j = 0; j < 2; ++j)
      reinterpret_cast<bf16x8*>(wstage)[j * 256 + tid] =
          reinterpret_cast<const bf16x8*>(wfr + (size_t)fb * 512)[j * 256 + tid];
    __syncthreads();
  }

  f32x4 b1q[4], b2q[4];
#pragma unroll
  for (int nt = 0; nt < 4; ++nt) {
    b1q[nt] = *reinterpret_cast<const f32x4*>(beu1 + nt * 16 + lg * 4);
    b2q[nt] = *reinterpret_cast<const f32x4*>(beu2 + nt * 16 + lg * 4);
  }

  float invn = 0.f;
  if constexpr (MODE == 0) invn = 1.0f / *norm_p;
  float nrm = 0.f, alp = 0.f, b2s = 0.f;
  if constexpr (MODE == 2) { nrm = *norm_p; alp = *alpha_p; b2s = *bd2_p; }

  // XCD-aware block swizzle (gridDim.x % 8 == 0)
  const int nb = gridDim.x, cpx = nb >> 3;
  const int bs = (blockIdx.x & 7) * cpx + (blockIdx.x >> 3);
  const int NWAVE = nb * 4;
  const int NG = NE / 16;

  int o, si, ri;
  bf16x8 pe0, pe1;
  float px = 0.f;
  auto prefetch = [&](int g) {
    int row = g * 16 + l15;
    int oo = col_idx[row];
    o = oo;
    si = senders[oo];
    ri = receivers[oo];
    if constexpr (MODE == 0) {
      px = edges_init[oo];
    } else {
      const bf16x8* er = reinterpret_cast<const bf16x8*>(e + (size_t)row * 64);
      pe0 = er[lg];
      pe1 = er[4 + lg];
    }
  };

  const int g0 = bs * 4 + wid;
  prefetch(g0);
  for (int g = g0; g < NG; g += NWAVE) {
    const int co = o, csi = si, cri = ri;
    bf16x8 ce0, ce1;
    float cx = 0.f;
    if constexpr (MODE == 0) cx = px;
    else { ce0 = pe0; ce1 = pe1; }
    // issue n gathers for current group
    const bf16x8* sp = reinterpret_cast<const bf16x8*>(n_bf + (size_t)csi * 64);
    bf16x8 as0 = sp[lg], as1 = sp[4 + lg];
    const bf16x8* rp = reinterpret_cast<const bf16x8*>(n_bf + (size_t)cri * 64);
    bf16x8 ar0 = rp[lg], ar1 = rp[4 + lg];
    int gn = g + NWAVE;
    if (gn < NG) prefetch(gn);

    if constexpr (MODE == 0) {
      // encoder: h as B-frag directly (lane: edge=l15, k=lg*8+i), e = h @ Wee2 + bee2
      float xv = cx * invn;
      bf16x8 h0, h1;
#pragma unroll
      for (int i = 0; i < 8; ++i) {
        h0[i] = (bf16_t)fmaxf(fmaf(xv, Wee1[lg * 8 + i], bee1[lg * 8 + i]), 0.0f);
        h1[i] = (bf16_t)fmaxf(fmaf(xv, Wee1[32 + lg * 8 + i], bee1[32 + lg * 8 + i]), 0.0f);
      }
      f32x4 ae[4];
#pragma unroll
      for (int nt = 0; nt < 4; ++nt)
        ae[nt] = *reinterpret_cast<const f32x4*>(bee2 + nt * 16 + lg * 4);
#pragma unroll
      for (int kt = 0; kt < 2; ++kt)
#pragma unroll
        for (int nt = 0; nt < 4; ++nt) {
          bf16x8 wf = *reinterpret_cast<const bf16x8*>(wstage + (kt * 4 + nt) * 512 + lane * 8);
          ae[nt] = __builtin_amdgcn_mfma_f32_16x16x32_bf16(wf, kt ? h1 : h0, ae[nt], 0, 0, 0);
        }
#pragma unroll
      for (int nt = 0; nt < 4; ++nt) {
        bf16x4 pk;
#pragma unroll
        for (int r = 0; r < 4; ++r) pk[r] = (bf16_t)ae[nt][r];
        *reinterpret_cast<bf16x4*>(&tr[wid][l15][nt * 16 + lg * 4]) = pk;
      }
      ce0 = *reinterpret_cast<const bf16x8*>(&tr[wid][l15][lg * 8]);
      ce1 = *reinterpret_cast<const bf16x8*>(&tr[wid][l15][32 + lg * 8]);
    }

    // layer 1: W from registers
    f32x4 acc[4];
#pragma unroll
    for (int nt = 0; nt < 4; ++nt) acc[nt] = b1q[nt];
    const bf16x8 mop[6] = {ce0, ce1, as0, as1, ar0, ar1};
#pragma unroll
    for (int kt = 0; kt < 6; ++kt)
#pragma unroll
      for (int nt = 0; nt < 4; ++nt)
        acc[nt] = __builtin_amdgcn_mfma_f32_16x16x32_bf16(W1r[kt * 4 + nt], mop[kt], acc[nt], 0, 0, 0);

    // relu -> transpose to B-frag
#pragma unroll
    for (int nt = 0; nt < 4; ++nt) {
      bf16x4 pk;
#pragma unroll
      for (int r = 0; r < 4; ++r) pk[r] = (bf16_t)fmaxf(acc[nt][r], 0.0f);
      *reinterpret_cast<bf16x4*>(&tr[wid][l15][nt * 16 + lg * 4]) = pk;
    }
    bf16x8 hh0 = *reinterpret_cast<const bf16x8*>(&tr[wid][l15][lg * 8]);
    bf16x8 hh1 = *reinterpret_cast<const bf16x8*>(&tr[wid][l15][32 + lg * 8]);

    // layer 2
    f32x4 acc2[4];
#pragma unroll
    for (int nt = 0; nt < 4; ++nt) acc2[nt] = b2q[nt];
#pragma unroll
    for (int kt = 0; kt < 2; ++kt)
#pragma unroll
      for (int nt = 0; nt < 4; ++nt)
        acc2[nt] = __builtin_amdgcn_mfma_f32_16x16x32_bf16(W2r[kt * 4 + nt], kt ? hh1 : hh0,
                                                           acc2[nt], 0, 0, 0);

    if constexpr (MODE == 2) {
      // decoder fused; final e never stored
#pragma unroll
      for (int nt = 0; nt < 4; ++nt) {
        bf16x4 pk;
#pragma unroll
        for (int r = 0; r < 4; ++r) pk[r] = (bf16_t)acc2[nt][r];
        *reinterpret_cast<bf16x4*>(&tr[wid][l15][nt * 16 + lg * 4]) = pk;
      }
      bf16x8 eb0 = *reinterpret_cast<const bf16x8*>(&tr[wid][l15][lg * 8]);
      bf16x8 eb1 = *reinterpret_cast<const bf16x8*>(&tr[wid][l15][32 + lg * 8]);
      f32x4 ad[4];
#pragma unroll
      for (int nt = 0; nt < 4; ++nt)
        ad[nt] = *reinterpret_cast<const f32x4*>(bd1 + nt * 16 + lg * 4);
#pragma unroll
      for (int kt = 0; kt < 2; ++kt)
#pragma unroll
        for (int nt = 0; nt < 4; ++nt) {
          bf16x8 wf = *reinterpret_cast<const bf16x8*>(wstage + (kt * 4 + nt) * 512 + lane * 8);
          ad[nt] = __builtin_amdgcn_mfma_f32_16x16x32_bf16(wf, kt ? eb1 : eb0, ad[nt], 0, 0, 0);
        }
      float s = 0.0f;
#pragma unroll
      for (int nt = 0; nt < 4; ++nt) {
        f32x4 w2 = *reinterpret_cast<const f32x4*>(Wd2 + nt * 16 + lg * 4);
#pragma unroll
        for (int r = 0; r < 4; ++r) s = fmaf(fmaxf(ad[nt][r], 0.0f), w2[r], s);
      }
      s += __shfl_xor(s, 16, 64);
      s += __shfl_xor(s, 32, 64);
      float ei = edges_init[co];
      if (lg == 0) {
        float dv = s + b2s;
        out[co] = (cri >= csi) ? fmaf(alp * nrm, dv, ei) : 0.0f;
      }
    } else {
      int row = g * 16 + l15;
#pragma unroll
      for (int nt = 0; nt < 4; ++nt) {
        bf16x4 pk;
#pragma unroll
        for (int r = 0; r < 4; ++r) pk[r] = (bf16_t)acc2[nt][r];
        *reinterpret_cast<bf16x4*>(e + (size_t)row * 64 + nt * 16 + lg * 4) = pk;
      }
    }
  }
}

// ---------------- node update: chunked coalesced agg + LDS weights ----------------
__global__ __launch_bounds__(256) void node_update_kernel(
    const bf16_t* __restrict__ e, const int* __restrict__ row_ptr,
    const float* __restrict__ Wnu1, const float* __restrict__ bnu1,
    const float* __restrict__ Wnu2, const float* __restrict__ bnu2,
    float* __restrict__ n_f32, bf16_t* __restrict__ n_bf) {
  __shared__ float w1[128 * 64];
  __shared__ float w2[64 * 64];
  __shared__ float xs[4][128];
  __shared__ float hs[4][64];
  const int tid = threadIdx.x, lane = tid & 63, wid = tid >> 6;
#pragma unroll
  for (int j = 0; j < 8; ++j)
    reinterpret_cast<float4*>(w1)[j * 256 + tid] =
        reinterpret_cast<const float4*>(Wnu1)[j * 256 + tid];
#pragma unroll
  for (int j = 0; j < 4; ++j)
    reinterpret_cast<float4*>(w2)[j * 256 + tid] =
        reinterpret_cast<const float4*>(Wnu2)[j * 256 + tid];
  __syncthreads();

  const int rsub = lane >> 3;  // row-within-chunk 0..7 (one chunk = 8 rows = 1024 B)
  for (int tile = blockIdx.x; tile < NN / 4; tile += gridDim.x) {
    const int node = tile * 4 + wid;
    const int p0 = row_ptr[node], cnt = row_ptr[node + 1] - p0;
    float a[8] = {0, 0, 0, 0, 0, 0, 0, 0};
    const bf16_t* base = e + (size_t)p0 * 64;
    const int nchunk = (cnt + 7) >> 3;  // 8 rows (64 lanes x 8 bf16 = 512 elems) per chunk
    for (int c = 0; c < nchunk; ++c) {
      bf16x8 v = *(reinterpret_cast<const bf16x8*>(base + (size_t)c * 512) + lane);
      if (c * 8 + rsub < cnt) {
#pragma unroll
        for (int i = 0; i < 8; ++i) a[i] += (float)v[i];
      }
    }
#pragma unroll
    for (int i = 0; i < 8; ++i) {  // reduce over rsub (lane bits 3,4,5)
      a[i] += __shfl_xor(a[i], 8, 64);
      a[i] += __shfl_xor(a[i], 16, 64);
      a[i] += __shfl_xor(a[i], 32, 64);
    }
    if (lane < 8) {  // lanes 0..7 (rsub=0) hold hidden dims lane*8+i
#pragma unroll
      for (int i = 0; i < 8; ++i) xs[wid][64 + lane * 8 + i] = a[i];
    }
    xs[wid][lane] = n_f32[(size_t)node * 64 + lane];
    float c0 = bnu1[lane], c1 = 0, c2 = 0, c3 = 0;
#pragma unroll 8
    for (int j = 0; j < 32; ++j) {
      c0 = fmaf(xs[wid][j],      w1[j * 64 + lane],        c0);
      c1 = fmaf(xs[wid][32 + j], w1[(32 + j) * 64 + lane], c1);
      c2 = fmaf(xs[wid][64 + j], w1[(64 + j) * 64 + lane], c2);
      c3 = fmaf(xs[wid][96 + j], w1[(96 + j) * 64 + lane], c3);
    }
    hs[wid][lane] = fmaxf((c0 + c1) + (c2 + c3), 0.0f);
    float d0 = bnu2[lane], d1 = 0;
#pragma unroll 8
    for (int j = 0; j < 32; ++j) {
      d0 = fmaf(hs[wid][j],      w2[j * 64 + lane],        d0);
      d1 = fmaf(hs[wid][32 + j], w2[(32 + j) * 64 + lane], d1);
    }
    float r = d0 + d1;
    n_f32[(size_t)node * 64 + lane] = r;
    n_bf[(size_t)node * 64 + lane] = (bf16_t)r;
  }
}

extern "C" void kernel_launch(void* const* d_in, const int* in_sizes, int n_in,
                              void* d_out, int out_size, void* d_ws, size_t ws_size,
                              hipStream_t stream) {
  const float* nodes      = (const float*)d_in[0];
  const float* edges_init = (const float*)d_in[1];
  const int*   receivers  = (const int*)d_in[2];
  const int*   senders    = (const int*)d_in[3];
  const float* Wne1 = (const float*)d_in[4];
  const float* bne1 = (const float*)d_in[5];
  const float* Wne2 = (const float*)d_in[6];
  const float* bne2 = (const float*)d_in[7];
  const float* Wee1 = (const float*)d_in[8];
  const float* bee1 = (const float*)d_in[9];
  const float* Wee2 = (const float*)d_in[10];
  const float* bee2 = (const float*)d_in[11];
  const float* Weu1 = (const float*)d_in[12];
  const float* beu1 = (const float*)d_in[13];
  const float* Weu2 = (const float*)d_in[14];
  const float* beu2 = (const float*)d_in[15];
  const float* Wnu1 = (const float*)d_in[16];
  const float* bnu1 = (const float*)d_in[17];
  const float* Wnu2 = (const float*)d_in[18];
  const float* bnu2 = (const float*)d_in[19];
  const float* Wd1  = (const float*)d_in[20];
  const float* bd1  = (const float*)d_in[21];
  const float* Wd2  = (const float*)d_in[22];
  const float* bd2  = (const float*)d_in[23];
  const float* alpha = (const float*)d_in[24];
  float* out = (float*)d_out;
  (void)in_sizes; (void)n_in; (void)out_size; (void)ws_size;

  char* ws = (char*)d_ws;
  size_t off = 0;
  auto alloc = [&](size_t bytes) -> void* {
    void* p = ws + off;
    off = (off + bytes + 255) & ~(size_t)255;
    return p;
  };
  float*  norm    = (float*)alloc(4);
  int*    counts  = (int*)alloc(sizeof(int) * NN);
  int*    row_ptr = (int*)alloc(sizeof(int) * (NN + 1));
  int*    cursor  = (int*)alloc(sizeof(int) * (NN + 1));
  int*    col_idx = (int*)alloc(sizeof(int) * NE);
  float*  n_f32   = (float*)alloc(sizeof(float) * (size_t)NN * 64);
  bf16_t* n_bf    = (bf16_t*)alloc(sizeof(bf16_t) * (size_t)NN * 64);
  bf16_t* e_buf   = (bf16_t*)alloc(sizeof(bf16_t) * (size_t)NE * 64 + 1024);  // +pad: node_update tail overread (<=896B)
  bf16_t* wfr     = (bf16_t*)alloc(sizeof(bf16_t) * 48 * 512);

  hipMemsetAsync(norm, 0, 4, stream);
  hipMemsetAsync(counts, 0, sizeof(int) * NN, stream);

  stats_kernel<<<1024, 256, 0, stream>>>(edges_init, receivers, norm, counts);
  prep_all_kernel<<<96, 256, 0, stream>>>(Weu1, Weu2, Wee2, Wd1, wfr);
  node_encode_kernel<<<NN / 4, 256, 0, stream>>>(nodes, Wne1, bne1, Wne2, bne2, n_f32, n_bf);
  scan_kernel<<<1, 1024, 0, stream>>>(counts, row_ptr, cursor);
  scatter_kernel<<<1024, 256, 0, stream>>>(receivers, cursor, col_idx);

  edge_update_kernel<0><<<2048, 256, 0, stream>>>(
      e_buf, n_bf, col_idx, senders, receivers, wfr, beu1, beu2,
      edges_init, norm, Wee1, bee1, bee2, bd1, Wd2, bd2, alpha, out);
  for (int t = 1; t <= 4; ++t) {
    node_update_kernel<<<2048, 256, 0, stream>>>(e_buf, row_ptr,
                                                 Wnu1, bnu1, Wnu2, bnu2, n_f32, n_bf);
    if (t < 4)
      edge_update_kernel<1><<<2048, 256, 0, stream>>>(
          e_buf, n_bf, col_idx, senders, receivers, wfr, beu1, beu2,
          edges_init, norm, Wee1, bee1, bee2, bd1, Wd2, bd2, alpha, out);
    else
      edge_update_kernel<2><<<2048, 256, 0, stream>>>(
          e_buf, n_bf, col_idx, senders, receivers, wfr, beu1, beu2,
          edges_init, norm, Wee1, bee1, bee2, bd1, Wd2, bd2, alpha, out);
  }
}